// Round 9
// baseline (9074.664 us; speedup 1.0000x reference)
//
#include <hip/hip_runtime.h>
#include <hip/hip_bf16.h>
#include <stdint.h>

#define B_   64
#define T_   1024
#define D_   300
#define H_   512
#define G4H  2048
#define KP   320   // K padded to multiple of 32 for the x-proj GEMM

typedef __attribute__((ext_vector_type(8))) short short8;   // 8 x bf16 (4 VGPRs)
typedef __attribute__((ext_vector_type(4))) float f32x4;
typedef unsigned long long ull;

__device__ __forceinline__ unsigned short f2bf(float v) {
    __hip_bfloat16 h = __float2bfloat16(v);
    return *reinterpret_cast<unsigned short*>(&h);
}
__device__ __forceinline__ float bf2f(unsigned u) {      // low 16 bits = bf16
    return __uint_as_float(u << 16);
}
__device__ __forceinline__ float sigm(float x) { return 1.f / (1.f + __expf(-x)); }
__device__ __forceinline__ float tanhfast(float x) {
    float e = __expf(2.f * x);            // inf-safe: x>>0 -> 1, x<<0 -> -1
    return 1.f - 2.f / (e + 1.f);
}

#define ASYNC16(g, l)                                                        \
    __builtin_amdgcn_global_load_lds(                                        \
        (const __attribute__((address_space(1))) void*)(g),                  \
        (__attribute__((address_space(3))) void*)(l), 16, 0, 0)

#define ALD(p) __hip_atomic_load((p), __ATOMIC_RELAXED, __HIP_MEMORY_SCOPE_AGENT)

// ---------------------------------------------------------------------------
// Kernel 1: essays fp32 [65536][300] -> bf16 [65536][320] (zero-padded K)
// ---------------------------------------------------------------------------
__global__ void cvt_essays(const float* __restrict__ es, unsigned short* __restrict__ Ab) {
    unsigned i = blockIdx.x * 256u + threadIdx.x;       // exactly 65536*320 threads
    unsigned row = i / KP;
    unsigned col = i - row * KP;
    float v = (col < D_) ? es[(size_t)row * D_ + col] : 0.f;
    Ab[i] = f2bf(v);
}

// ---------------------------------------------------------------------------
// Kernel 2: Wx transpose+pad -> bf16 WxT[2048][320]
// ---------------------------------------------------------------------------
__global__ void cvt_misc(const float* __restrict__ Wl, unsigned short* __restrict__ Bt) {
    unsigned i = blockIdx.x * 256u + threadIdx.x;       // exactly 2048*320 threads
    unsigned n = i / KP, k = i - n * KP;
    float v = (k < D_) ? Wl[(size_t)k * G4H + n] : 0.f;   // Wx rows 0..299
    Bt[i] = f2bf(v);
}

// ---------------------------------------------------------------------------
// Kernel 2b: Wh transpose -> bf16 WhTg[2048][512]; init h exchange buffers.
// hswz tag 0xFFFF never matches any want tag (t <= 1023; stores 1..1024).
// NOTE: hswz must NOT alias Ab (R7 bug: init NaN-poisoned the A matrix).
// ---------------------------------------------------------------------------
__global__ void cvt_wh(const float* __restrict__ Wl, unsigned short* __restrict__ WhTg,
                       unsigned* __restrict__ hswz) {
    unsigned i = blockIdx.x * 256u + threadIdx.x;       // 2048*512 threads
    unsigned gc = i & 2047u, k = i >> 11;
    WhTg[(size_t)gc * 512 + k] = f2bf(Wl[(size_t)(300 + k) * G4H + gc]);
    if (i < 65536u) hswz[i] = 0x0000FFFFu;              // both buffers invalid
}

// ---------------------------------------------------------------------------
// Kernel 3: x_proj GEMM -> xpr in recurrence layout:
//   xpr[((t*4+g)*32+slice)*1024 + b*64 + jj*4 + gate]   (bf16, bias added)
// where row = (g*16+b)*1024 + t, col = gate*512 + slice*16 + jj.
// Consumer lane then reads its 4 gates in one 8-B load.
// ---------------------------------------------------------------------------
__global__ __launch_bounds__(256) void gemm_xp(
    const unsigned short* __restrict__ Ab,   // [65536][320] bf16
    const unsigned short* __restrict__ Bt,   // [2048][320]  bf16 (WxT)
    const float* __restrict__ bias,          // [2048]
    unsigned short* __restrict__ xpr)        // [65536*2048] bf16, permuted
{
    __shared__ __align__(16) unsigned short Al[128 * 32];
    __shared__ __align__(16) unsigned short Bl[128 * 32];
    const int tid = threadIdx.x;
    const int w = tid >> 6, lane = tid & 63;
    const int ln = lane & 15, q = lane >> 4;
    const int bx = blockIdx.x;
    const int m0 = (bx >> 4) * 128;          // consecutive blocks share the A tile
    const int n0 = (bx & 15) * 128;
    const int wr = w >> 1, wc = w & 1;

    f32x4 acc[4][4];
#pragma unroll
    for (int i = 0; i < 4; i++)
#pragma unroll
        for (int j = 0; j < 4; j++) acc[i][j] = (f32x4){0.f, 0.f, 0.f, 0.f};

    for (int k0 = 0; k0 < KP; k0 += 32) {
#pragma unroll
        for (int it = 0; it < 2; ++it) {
            int s = it * 4 + w;              // wave-uniform segment id
            int c = s * 64 + lane;           // 16B chunk id, 0..511
            int r = c >> 2;                  // tile row 0..127
            int ko = (c & 3) * 8;            // k offset in elements
            ASYNC16(Ab + (size_t)(m0 + r) * KP + k0 + ko, &Al[s * 512]);
            ASYNC16(Bt + (size_t)(n0 + r) * KP + k0 + ko, &Bl[s * 512]);
        }
        __syncthreads();
        short8 af[4], bf[4];
#pragma unroll
        for (int mt = 0; mt < 4; ++mt)
            af[mt] = *(const short8*)&Al[(wr * 64 + mt * 16 + ln) * 32 + q * 8];
#pragma unroll
        for (int nt = 0; nt < 4; ++nt)
            bf[nt] = *(const short8*)&Bl[(wc * 64 + nt * 16 + ln) * 32 + q * 8];
#pragma unroll
        for (int mt = 0; mt < 4; ++mt)
#pragma unroll
            for (int nt = 0; nt < 4; ++nt)
                acc[mt][nt] = __builtin_amdgcn_mfma_f32_16x16x32_bf16(af[mt], bf[nt], acc[mt][nt], 0, 0, 0);
        __syncthreads();
    }
#pragma unroll
    for (int mt = 0; mt < 4; ++mt) {
#pragma unroll
        for (int nt = 0; nt < 4; ++nt) {
            int col = n0 + wc * 64 + nt * 16 + ln;
            int gate = col >> 9, r9 = col & 511;
            int slice = r9 >> 4, jj = r9 & 15;
            float bb = bias[col];
#pragma unroll
            for (int r = 0; r < 4; ++r) {
                int row = m0 + wr * 64 + mt * 16 + q * 4 + r;   // C/D: col=lane&15, row=quad*4+reg
                int t = row & 1023, bglob = row >> 10;
                int g = bglob >> 4, bloc = bglob & 15;
                size_t idx = ((((size_t)t * 4 + g) * 32 + slice) * 16 + bloc) * 64
                             + jj * 4 + gate;
                xpr[idx] = f2bf(acc[mt][nt][r] + bb);
            }
        }
    }
}

// ---------------------------------------------------------------------------
// Kernel 4: persistent LSTM recurrence — single wave per slice, no LDS, no
// barriers. 4 groups x 32 slices = 128 blocks x 64 threads.
// Wh fragments (4 gates x 16 k-chunks x short8 = 256 regs) resident in the
// unified VGPR/AGPR file. h exchange: one dword per element =
// (bf16(h)<<16)|tag16 (value bit-exact, tag = producing step). Buffer is
// SWIZZLED into A-fragment order hswz[buf][g][kk][q][ln][e]; the poll IS the
// fragment load (fully coalesced).
// POLL IS PHASE-BATCHED (R8 lesson): issue all 64 loads; check all 16 chunks;
// re-issue ALL bad chunks at once; re-check. Lockstep blocks make round 1
// stale, round 2 good => ~2 RTs/step, not 16 serialized RTs.
// Skew <= 1 step (writer of tag t+3 validated all of h(t+2)) => buf reuse safe.
// All 4 gate N-tiles share the C/D lane map -> elementwise fully in-register.
// ---------------------------------------------------------------------------
__global__ __launch_bounds__(64, 1) void lstm_rec(
    const unsigned short* __restrict__ WhTg, // [2048][512] bf16 (pre-transposed Wh)
    const unsigned short* __restrict__ xpr,  // permuted x_proj (see gemm_xp)
    unsigned* __restrict__ hswz,             // [2][4][16][4][16][8] tagged dwords
    float* __restrict__ hmean)               // [64][512] fp32
{
    const int bid = blockIdx.x;
    const int g     = bid >> 5;        // batch group 0..3
    const int slice = bid & 31;        // j-slice 0..31
    const int j0    = slice * 16;
    const int bg    = g * 16;
    const int lane = threadIdx.x, ln = lane & 15, q = lane >> 4;

    // permanent B-fragments: bw[gate*16+kk], lane(q,ln) = B[n=ln][k=kk*32+q*8+..]
    short8 bw[64];
#pragma unroll
    for (int gate = 0; gate < 4; ++gate)
#pragma unroll
        for (int kk = 0; kk < 16; ++kk)
            bw[gate * 16 + kk] =
                *(const short8*)&WhTg[(size_t)(gate * 512 + j0 + ln) * 512 + kk * 32 + q * 8];

    float c_[4] = {0.f, 0.f, 0.f, 0.f};
    float hs[4] = {0.f, 0.f, 0.f, 0.f};

    // consumer poll base (ull index): [g][kk][q][ln][e] -> g*4096 + kk*256 + q*64 + ln*4
    const int csrc = g * 4096 + q * 64 + ln * 4;
    // producer store base (dword index): k = slice*16+ln -> (kk_s,q_s,e_s); row b = q*4+r
    const int kel = j0 + ln;
    const int sdst = g * 8192 + (kel >> 5) * 512 + ((kel >> 3) & 3) * 128 + q * 32 + (kel & 7);

    const unsigned short* xreg0 = xpr + ((size_t)g * 32 + slice) * 1024;
    ull xc[4], xn[4];
#pragma unroll
    for (int r = 0; r < 4; ++r)
        xc[r] = *(const ull*)(xreg0 + (4 * q + r) * 64 + ln * 4);

    for (int t = 0; t < T_; ++t) {
        // prefetch xp(t+1): 4 gates per element in one 8-B load
        if (t + 1 < T_) {
            const unsigned short* xr = xreg0 + (size_t)(t + 1) * 131072;  // 4*32*1024
#pragma unroll
            for (int r = 0; r < 4; ++r)
                xn[r] = *(const ull*)(xr + (4 * q + r) * 64 + ln * 4);
        }

        f32x4 acc0 = (f32x4){0.f, 0.f, 0.f, 0.f};
        f32x4 acc1 = (f32x4){0.f, 0.f, 0.f, 0.f};
        f32x4 acc2 = (f32x4){0.f, 0.f, 0.f, 0.f};
        f32x4 acc3 = (f32x4){0.f, 0.f, 0.f, 0.f};

        if (t > 0) {
            const ull* hb = (const ull*)hswz + (size_t)(t & 1) * 16384 + csrc;
            const unsigned wt = (unsigned)t;             // want tag
            ull v[64];
            // round 0: issue ALL 64 chunk loads (max MLP, fully coalesced)
#pragma unroll
            for (int kk = 0; kk < 16; ++kk)
#pragma unroll
                for (int i = 0; i < 4; ++i)
                    v[kk * 4 + i] = ALD(hb + kk * 256 + i);
            // phase-batched validate: re-issue ALL bad chunks together each round
            while (true) {
                unsigned nb = 0u;
#pragma unroll
                for (int kk = 0; kk < 16; ++kk) {
                    ull a0 = v[kk * 4], a1 = v[kk * 4 + 1];
                    ull a2 = v[kk * 4 + 2], a3 = v[kk * 4 + 3];
                    unsigned bad =
                        (((unsigned)a0 ^ wt) | ((unsigned)(a0 >> 32) ^ wt) |
                         ((unsigned)a1 ^ wt) | ((unsigned)(a1 >> 32) ^ wt) |
                         ((unsigned)a2 ^ wt) | ((unsigned)(a2 >> 32) ^ wt) |
                         ((unsigned)a3 ^ wt) | ((unsigned)(a3 >> 32) ^ wt)) & 0xffffu;
                    nb |= bad ? (1u << kk) : 0u;
                }
                if (nb == 0u) break;
#pragma unroll
                for (int kk = 0; kk < 16; ++kk)
                    if (nb & (1u << kk))
#pragma unroll
                        for (int i = 0; i < 4; ++i)
                            v[kk * 4 + i] = ALD(hb + kk * 256 + i);
            }
            // consume: unpack (value in high 16 bits) + 4 interleaved MFMA chains
#pragma unroll
            for (int kk = 0; kk < 16; ++kk) {
                ull a0 = v[kk * 4], a1 = v[kk * 4 + 1];
                ull a2 = v[kk * 4 + 2], a3 = v[kk * 4 + 3];
                union { unsigned u[4]; short8 s; } cv;
                cv.u[0] = __builtin_amdgcn_perm((unsigned)(a0 >> 32), (unsigned)a0, 0x07060302u);
                cv.u[1] = __builtin_amdgcn_perm((unsigned)(a1 >> 32), (unsigned)a1, 0x07060302u);
                cv.u[2] = __builtin_amdgcn_perm((unsigned)(a2 >> 32), (unsigned)a2, 0x07060302u);
                cv.u[3] = __builtin_amdgcn_perm((unsigned)(a3 >> 32), (unsigned)a3, 0x07060302u);
                short8 af = cv.s;
                acc0 = __builtin_amdgcn_mfma_f32_16x16x32_bf16(af, bw[kk],      acc0, 0, 0, 0);
                acc1 = __builtin_amdgcn_mfma_f32_16x16x32_bf16(af, bw[16 + kk], acc1, 0, 0, 0);
                acc2 = __builtin_amdgcn_mfma_f32_16x16x32_bf16(af, bw[32 + kk], acc2, 0, 0, 0);
                acc3 = __builtin_amdgcn_mfma_f32_16x16x32_bf16(af, bw[48 + kk], acc3, 0, 0, 0);
            }
        }

        // elementwise: lane handles (b = q*4+r, j = j0+ln), r = 0..3
        unsigned* hdst = hswz + (size_t)((t + 1) & 1) * 32768 + sdst;
        const unsigned newtag = (unsigned)(t + 1);
#pragma unroll
        for (int r = 0; r < 4; ++r) {
            float ai  = acc0[r] + bf2f((unsigned)xc[r] & 0xffffu);
            float aj  = acc1[r] + bf2f(((unsigned)xc[r]) >> 16);
            float af_ = acc2[r] + bf2f((unsigned)(xc[r] >> 32) & 0xffffu);
            float ao  = acc3[r] + bf2f((unsigned)(xc[r] >> 48));
            float si = sigm(ai), tj = tanhfast(aj);
            float sf = sigm(af_ + 1.0f), so = sigm(ao);
            c_[r] = c_[r] * sf + si * tj;
            float h = tanhfast(c_[r]) * so;
            hs[r] += h;
            unsigned hv = ((unsigned)f2bf(h) << 16) | newtag;   // exact value + tag
            __hip_atomic_store(hdst + r * 8, hv, __ATOMIC_RELAXED, __HIP_MEMORY_SCOPE_AGENT);
            xc[r] = xn[r];
        }
    }
#pragma unroll
    for (int r = 0; r < 4; ++r)
        hmean[(size_t)(bg + 4 * q + r) * 512 + j0 + ln] = hs[r] * (1.f / 1024.f);
}

// ---------------------------------------------------------------------------
// Kernel 5: preds = sigmoid(hmean @ W_dense + b_dense), one wave per batch row
// ---------------------------------------------------------------------------
__global__ void dense_out(const float* __restrict__ hmean, const float* __restrict__ Wd,
                          const float* __restrict__ bd, float* __restrict__ out) {
    int bb = blockIdx.x;
    int lane = threadIdx.x;
    float p = 0.f;
    for (int e = lane; e < H_; e += 64) p += hmean[(size_t)bb * H_ + e] * Wd[e];
#pragma unroll
    for (int off = 32; off; off >>= 1) p += __shfl_down(p, off);
    if (lane == 0) out[bb] = 1.f / (1.f + __expf(-(p + bd[0])));
}

// ---------------------------------------------------------------------------
extern "C" void kernel_launch(void* const* d_in, const int* in_sizes, int n_in,
                              void* d_out, int out_size, void* d_ws, size_t ws_size,
                              hipStream_t stream) {
    const float* essays  = (const float*)d_in[0];
    const float* W_lstm  = (const float*)d_in[1];
    const float* b_lstm  = (const float*)d_in[2];
    const float* W_dense = (const float*)d_in[3];
    const float* b_dense = (const float*)d_in[4];
    float* out = (float*)d_out;

    char* ws = (char*)d_ws;
    unsigned short* xp   = (unsigned short*)(ws);                   // 256 MB (permuted)
    unsigned short* Ab   = (unsigned short*)(ws + 268435456ull);    // 40 MB (dead after gemm_xp)
    unsigned short* Bt   = (unsigned short*)(ws + 310378496ull);    // 1.25 MB
    unsigned short* WhTg = (unsigned short*)(ws + 311689216ull);    // 2 MB -> ends 313786368
    unsigned*       hswz = (unsigned*)(ws + 313786368ull);          // 256 KB -> ends 314048512
    float*          hm   = (float*)(ws + 268435456ull);             // 128 KB (overlaps dead Ab)

    hipLaunchKernelGGL(cvt_essays, dim3(81920), dim3(256), 0, stream, essays, Ab);
    hipLaunchKernelGGL(cvt_misc,   dim3(2560),  dim3(256), 0, stream, W_lstm, Bt);
    hipLaunchKernelGGL(cvt_wh,     dim3(4096),  dim3(256), 0, stream, W_lstm, WhTg, hswz);
    hipLaunchKernelGGL(gemm_xp,    dim3(8192),  dim3(256), 0, stream, Ab, Bt, b_lstm, xp);
    hipLaunchKernelGGL(lstm_rec,   dim3(128),   dim3(64),  0, stream, WhTg, xp, hswz, hm);
    hipLaunchKernelGGL(dense_out,  dim3(64),    dim3(64),  0, stream, hm, W_dense, b_dense, out);
}

// Round 10
// 3846.495 us; speedup vs baseline: 2.3592x; 2.3592x over previous
//
#include <hip/hip_runtime.h>
#include <hip/hip_bf16.h>
#include <stdint.h>

#define B_   64
#define T_   1024
#define D_   300
#define H_   512
#define G4H  2048
#define KP   320   // K padded to multiple of 32 for the x-proj GEMM

typedef __attribute__((ext_vector_type(8))) short short8;   // 8 x bf16 (4 VGPRs)
typedef __attribute__((ext_vector_type(4))) float f32x4;
typedef unsigned long long ull;

__device__ __forceinline__ unsigned short f2bf(float v) {
    __hip_bfloat16 h = __float2bfloat16(v);
    return *reinterpret_cast<unsigned short*>(&h);
}
__device__ __forceinline__ float bf2f(unsigned u) {      // low 16 bits = bf16
    return __uint_as_float(u << 16);
}
__device__ __forceinline__ float sigm(float x) { return 1.f / (1.f + __expf(-x)); }
__device__ __forceinline__ float tanhfast(float x) {
    float e = __expf(2.f * x);            // inf-safe: x>>0 -> 1, x<<0 -> -1
    return 1.f - 2.f / (e + 1.f);
}

#define ASYNC16(g, l)                                                        \
    __builtin_amdgcn_global_load_lds(                                        \
        (const __attribute__((address_space(1))) void*)(g),                  \
        (__attribute__((address_space(3))) void*)(l), 16, 0, 0)

#define ALD(p) __hip_atomic_load((p), __ATOMIC_RELAXED, __HIP_MEMORY_SCOPE_AGENT)

// ---------------------------------------------------------------------------
// Kernel 1: essays fp32 [65536][300] -> bf16 [65536][320] (zero-padded K)
// ---------------------------------------------------------------------------
__global__ void cvt_essays(const float* __restrict__ es, unsigned short* __restrict__ Ab) {
    unsigned i = blockIdx.x * 256u + threadIdx.x;       // exactly 65536*320 threads
    unsigned row = i / KP;
    unsigned col = i - row * KP;
    float v = (col < D_) ? es[(size_t)row * D_ + col] : 0.f;
    Ab[i] = f2bf(v);
}

// ---------------------------------------------------------------------------
// Kernel 2: Wx transpose+pad -> bf16 WxT[2048][320]
// ---------------------------------------------------------------------------
__global__ void cvt_misc(const float* __restrict__ Wl, unsigned short* __restrict__ Bt) {
    unsigned i = blockIdx.x * 256u + threadIdx.x;       // exactly 2048*320 threads
    unsigned n = i / KP, k = i - n * KP;
    float v = (k < D_) ? Wl[(size_t)k * G4H + n] : 0.f;   // Wx rows 0..299
    Bt[i] = f2bf(v);
}

// ---------------------------------------------------------------------------
// Kernel 2b: Wh transpose -> bf16 WhTg[2048][512]; init h exchange buffers.
// hswz tag 0xFFFF never matches any want tag (t <= 1023; stores 1..1024).
// NOTE: hswz must NOT alias Ab (R7 bug: init NaN-poisoned the A matrix).
// ---------------------------------------------------------------------------
__global__ void cvt_wh(const float* __restrict__ Wl, unsigned short* __restrict__ WhTg,
                       unsigned* __restrict__ hswz) {
    unsigned i = blockIdx.x * 256u + threadIdx.x;       // 2048*512 threads
    unsigned gc = i & 2047u, k = i >> 11;
    WhTg[(size_t)gc * 512 + k] = f2bf(Wl[(size_t)(300 + k) * G4H + gc]);
    if (i < 65536u) hswz[i] = 0x0000FFFFu;              // both buffers invalid
}

// ---------------------------------------------------------------------------
// Kernel 3: x_proj GEMM -> xpr in recurrence layout:
//   xpr[((t*4+g)*32+slice)*1024 + b*64 + jj*4 + gate]   (bf16, bias added)
// where row = (g*16+b)*1024 + t, col = gate*512 + slice*16 + jj.
// Consumer lane then reads its 4 gates in one 8-B load.
// ---------------------------------------------------------------------------
__global__ __launch_bounds__(256) void gemm_xp(
    const unsigned short* __restrict__ Ab,   // [65536][320] bf16
    const unsigned short* __restrict__ Bt,   // [2048][320]  bf16 (WxT)
    const float* __restrict__ bias,          // [2048]
    unsigned short* __restrict__ xpr)        // [65536*2048] bf16, permuted
{
    __shared__ __align__(16) unsigned short Al[128 * 32];
    __shared__ __align__(16) unsigned short Bl[128 * 32];
    const int tid = threadIdx.x;
    const int w = tid >> 6, lane = tid & 63;
    const int ln = lane & 15, q = lane >> 4;
    const int bx = blockIdx.x;
    const int m0 = (bx >> 4) * 128;          // consecutive blocks share the A tile
    const int n0 = (bx & 15) * 128;
    const int wr = w >> 1, wc = w & 1;

    f32x4 acc[4][4];
#pragma unroll
    for (int i = 0; i < 4; i++)
#pragma unroll
        for (int j = 0; j < 4; j++) acc[i][j] = (f32x4){0.f, 0.f, 0.f, 0.f};

    for (int k0 = 0; k0 < KP; k0 += 32) {
#pragma unroll
        for (int it = 0; it < 2; ++it) {
            int s = it * 4 + w;              // wave-uniform segment id
            int c = s * 64 + lane;           // 16B chunk id, 0..511
            int r = c >> 2;                  // tile row 0..127
            int ko = (c & 3) * 8;            // k offset in elements
            ASYNC16(Ab + (size_t)(m0 + r) * KP + k0 + ko, &Al[s * 512]);
            ASYNC16(Bt + (size_t)(n0 + r) * KP + k0 + ko, &Bl[s * 512]);
        }
        __syncthreads();
        short8 af[4], bf[4];
#pragma unroll
        for (int mt = 0; mt < 4; ++mt)
            af[mt] = *(const short8*)&Al[(wr * 64 + mt * 16 + ln) * 32 + q * 8];
#pragma unroll
        for (int nt = 0; nt < 4; ++nt)
            bf[nt] = *(const short8*)&Bl[(wc * 64 + nt * 16 + ln) * 32 + q * 8];
#pragma unroll
        for (int mt = 0; mt < 4; ++mt)
#pragma unroll
            for (int nt = 0; nt < 4; ++nt)
                acc[mt][nt] = __builtin_amdgcn_mfma_f32_16x16x32_bf16(af[mt], bf[nt], acc[mt][nt], 0, 0, 0);
        __syncthreads();
    }
#pragma unroll
    for (int mt = 0; mt < 4; ++mt) {
#pragma unroll
        for (int nt = 0; nt < 4; ++nt) {
            int col = n0 + wc * 64 + nt * 16 + ln;
            int gate = col >> 9, r9 = col & 511;
            int slice = r9 >> 4, jj = r9 & 15;
            float bb = bias[col];
#pragma unroll
            for (int r = 0; r < 4; ++r) {
                int row = m0 + wr * 64 + mt * 16 + q * 4 + r;   // C/D: col=lane&15, row=quad*4+reg
                int t = row & 1023, bglob = row >> 10;
                int g = bglob >> 4, bloc = bglob & 15;
                size_t idx = ((((size_t)t * 4 + g) * 32 + slice) * 16 + bloc) * 64
                             + jj * 4 + gate;
                xpr[idx] = f2bf(acc[mt][nt][r] + bb);
            }
        }
    }
}

// ---------------------------------------------------------------------------
// Kernel 4: persistent LSTM recurrence — 4 groups x 8 blocks x 256 threads.
// Each of the 4 waves owns one 16-j slice: its 64 Wh gate-columns live in
// 256 registers (launch_bounds(256,1) -> 1 wave/SIMD, 512-VGPR budget).
// Protocol (proven in R8/9): h element = dword (bf16(h)<<16)|tag16 in
// hswz[buf][g][kk][q][ln][e] (A-fragment order); skew <= 1 step => 2-buffer
// reuse safe; init tag 0xFFFF invalid.
// Poll is COOPERATIVE (R5's proven MLP): 256 threads x 16 ull, batched
// laggard retry, then packed bf16 written to a DOUBLE-BUFFERED LDS mirror in
// fragment order (no second sync needed). One __syncthreads per step; each
// wave ds_read_b128's the shared A-fragments (conflict-free) and runs its
// 64 MFMAs; all 4 gates land in the same lane -> elementwise in-register.
// ---------------------------------------------------------------------------
__global__ __launch_bounds__(256, 1) void lstm_rec(
    const unsigned short* __restrict__ WhTg, // [2048][512] bf16 (pre-transposed Wh)
    const unsigned short* __restrict__ xpr,  // permuted x_proj (see gemm_xp)
    unsigned* __restrict__ hswz,             // [2][4][16][4][16][8] tagged dwords
    float* __restrict__ hmean)               // [64][512] fp32
{
    __shared__ __align__(16) unsigned hl[2][4096];   // packed bf16 pairs, frag order

    const int bid = blockIdx.x;
    const int g   = bid >> 3;          // batch group 0..3
    const int blk = bid & 7;           // block within group
    const int tid = threadIdx.x;
    const int wv  = tid >> 6;
    const int lane = tid & 63, ln = lane & 15, q = lane >> 4;
    const int slice = blk * 4 + wv;    // 0..31
    const int j0 = slice * 16;
    const int bg = g * 16;

    // wave-resident B-fragments: bw[gate*16+kk], lane(q,ln)=B[n=ln][k=kk*32+q*8..]
    short8 bw[64];
#pragma unroll
    for (int gate = 0; gate < 4; ++gate)
#pragma unroll
        for (int kk = 0; kk < 16; ++kk)
            bw[gate * 16 + kk] =
                *(const short8*)&WhTg[(size_t)(gate * 512 + j0 + ln) * 512 + kk * 32 + q * 8];

    float c_[4] = {0.f, 0.f, 0.f, 0.f};
    float hs[4] = {0.f, 0.f, 0.f, 0.f};

    // producer store base (dword idx): element (b=q*4+r, k=j0+ln)
    const int kel = j0 + ln;
    const int sdst = g * 8192 + (kel >> 5) * 512 + ((kel >> 3) & 3) * 128 + q * 32 + (kel & 7);

    const unsigned short* xreg0 = xpr + ((size_t)g * 32 + slice) * 1024;
    ull xc[4], xn[4];
#pragma unroll
    for (int r = 0; r < 4; ++r)
        xc[r] = *(const ull*)(xreg0 + (4 * q + r) * 64 + ln * 4);

    for (int t = 0; t < T_; ++t) {
        // prefetch xp(t+1): 4 gates per element in one 8-B load
        if (t + 1 < T_) {
            const unsigned short* xr = xreg0 + (size_t)(t + 1) * 131072;  // 4*32*1024
#pragma unroll
            for (int r = 0; r < 4; ++r)
                xn[r] = *(const ull*)(xr + (4 * q + r) * 64 + ln * 4);
        }

        if (t > 0) {
            // cooperative poll of the group's h(t): 16 ull per thread, coalesced
            const ull* hb = (const ull*)hswz + (size_t)(t & 1) * 16384 + g * 4096;
            const unsigned wt = (unsigned)t;
            ull v[16];
#pragma unroll
            for (int i = 0; i < 16; ++i)
                v[i] = ALD(hb + tid + (i << 8));
            while (true) {                        // batched laggard retry
                unsigned nb = 0u;
#pragma unroll
                for (int i = 0; i < 16; ++i) {
                    unsigned bad = (((unsigned)v[i] ^ wt) |
                                    ((unsigned)(v[i] >> 32) ^ wt)) & 0xffffu;
                    nb |= bad ? (1u << i) : 0u;
                }
                if (nb == 0u) break;
#pragma unroll
                for (int i = 0; i < 16; ++i)
                    if (nb & (1u << i))
                        v[i] = ALD(hb + tid + (i << 8));
            }
            // stage packed bf16 pairs into the fragment-order LDS mirror
            unsigned* dst = hl[t & 1];
#pragma unroll
            for (int i = 0; i < 16; ++i)
                dst[tid + (i << 8)] =
                    __builtin_amdgcn_perm((unsigned)(v[i] >> 32), (unsigned)v[i], 0x07060302u);
        }
        __syncthreads();

        f32x4 acc0 = (f32x4){0.f, 0.f, 0.f, 0.f};
        f32x4 acc1 = (f32x4){0.f, 0.f, 0.f, 0.f};
        f32x4 acc2 = (f32x4){0.f, 0.f, 0.f, 0.f};
        f32x4 acc3 = (f32x4){0.f, 0.f, 0.f, 0.f};
        if (t > 0) {
            const unsigned* src = hl[t & 1];
#pragma unroll
            for (int kk = 0; kk < 16; ++kk) {
                short8 af = *(const short8*)&src[kk * 256 + q * 64 + ln * 4];
                acc0 = __builtin_amdgcn_mfma_f32_16x16x32_bf16(af, bw[kk],      acc0, 0, 0, 0);
                acc1 = __builtin_amdgcn_mfma_f32_16x16x32_bf16(af, bw[16 + kk], acc1, 0, 0, 0);
                acc2 = __builtin_amdgcn_mfma_f32_16x16x32_bf16(af, bw[32 + kk], acc2, 0, 0, 0);
                acc3 = __builtin_amdgcn_mfma_f32_16x16x32_bf16(af, bw[48 + kk], acc3, 0, 0, 0);
            }
        }

        // elementwise: lane handles (b = q*4+r, j = j0+ln), r = 0..3
        unsigned* hdst = hswz + (size_t)((t + 1) & 1) * 32768 + sdst;
        const unsigned newtag = (unsigned)(t + 1);
#pragma unroll
        for (int r = 0; r < 4; ++r) {
            float ai  = acc0[r] + bf2f((unsigned)xc[r] & 0xffffu);
            float aj  = acc1[r] + bf2f(((unsigned)xc[r]) >> 16);
            float af_ = acc2[r] + bf2f((unsigned)(xc[r] >> 32) & 0xffffu);
            float ao  = acc3[r] + bf2f((unsigned)(xc[r] >> 48));
            float si = sigm(ai), tj = tanhfast(aj);
            float sf = sigm(af_ + 1.0f), so = sigm(ao);
            c_[r] = c_[r] * sf + si * tj;
            float h = tanhfast(c_[r]) * so;
            hs[r] += h;
            unsigned hv = ((unsigned)f2bf(h) << 16) | newtag;   // exact value + tag
            __hip_atomic_store(hdst + r * 8, hv, __ATOMIC_RELAXED, __HIP_MEMORY_SCOPE_AGENT);
            xc[r] = xn[r];
        }
    }
#pragma unroll
    for (int r = 0; r < 4; ++r)
        hmean[(size_t)(bg + 4 * q + r) * 512 + j0 + ln] = hs[r] * (1.f / 1024.f);
}

// ---------------------------------------------------------------------------
// Kernel 5: preds = sigmoid(hmean @ W_dense + b_dense), one wave per batch row
// ---------------------------------------------------------------------------
__global__ void dense_out(const float* __restrict__ hmean, const float* __restrict__ Wd,
                          const float* __restrict__ bd, float* __restrict__ out) {
    int bb = blockIdx.x;
    int lane = threadIdx.x;
    float p = 0.f;
    for (int e = lane; e < H_; e += 64) p += hmean[(size_t)bb * H_ + e] * Wd[e];
#pragma unroll
    for (int off = 32; off; off >>= 1) p += __shfl_down(p, off);
    if (lane == 0) out[bb] = 1.f / (1.f + __expf(-(p + bd[0])));
}

// ---------------------------------------------------------------------------
extern "C" void kernel_launch(void* const* d_in, const int* in_sizes, int n_in,
                              void* d_out, int out_size, void* d_ws, size_t ws_size,
                              hipStream_t stream) {
    const float* essays  = (const float*)d_in[0];
    const float* W_lstm  = (const float*)d_in[1];
    const float* b_lstm  = (const float*)d_in[2];
    const float* W_dense = (const float*)d_in[3];
    const float* b_dense = (const float*)d_in[4];
    float* out = (float*)d_out;

    char* ws = (char*)d_ws;
    unsigned short* xp   = (unsigned short*)(ws);                   // 256 MB (permuted)
    unsigned short* Ab   = (unsigned short*)(ws + 268435456ull);    // 40 MB (dead after gemm_xp)
    unsigned short* Bt   = (unsigned short*)(ws + 310378496ull);    // 1.25 MB
    unsigned short* WhTg = (unsigned short*)(ws + 311689216ull);    // 2 MB -> ends 313786368
    unsigned*       hswz = (unsigned*)(ws + 313786368ull);          // 256 KB -> ends 314048512
    float*          hm   = (float*)(ws + 268435456ull);             // 128 KB (overlaps dead Ab)

    hipLaunchKernelGGL(cvt_essays, dim3(81920), dim3(256), 0, stream, essays, Ab);
    hipLaunchKernelGGL(cvt_misc,   dim3(2560),  dim3(256), 0, stream, W_lstm, Bt);
    hipLaunchKernelGGL(cvt_wh,     dim3(4096),  dim3(256), 0, stream, W_lstm, WhTg, hswz);
    hipLaunchKernelGGL(gemm_xp,    dim3(8192),  dim3(256), 0, stream, Ab, Bt, b_lstm, xp);
    hipLaunchKernelGGL(lstm_rec,   dim3(32),    dim3(256), 0, stream, WhTg, xp, hswz, hm);
    hipLaunchKernelGGL(dense_out,  dim3(64),    dim3(64),  0, stream, hm, W_dense, b_dense, out);
}